// Round 1
// baseline (900.283 us; speedup 1.0000x reference)
//
#include <hip/hip_runtime.h>

// GCN layer: out = relu(scatter_add(edge_val * (x@W + b)[edge_col] -> edge_row))
// N=100000 nodes, E=1600000 edges, 256 -> 128 features, all fp32.

constexpr int kNodes = 100000;
constexpr int kEdges = 1600000;
constexpr int kInF   = 256;
constexpr int kOutF  = 128;

// ---------------------------------------------------------------------------
// GEMM: support[N][128] = x[N][256] @ W[256][128] + b
// Block: 256 threads, tile 64 rows x 128 cols, K staged in chunks of 16.
// Each thread computes a 4x8 register tile. fp32 (no fp32 MFMA on CDNA4).
// ---------------------------------------------------------------------------
__global__ __launch_bounds__(256) void gcn_gemm(const float* __restrict__ x,
                                                const float* __restrict__ W,
                                                const float* __restrict__ b,
                                                float* __restrict__ support) {
    __shared__ float xT[16][64];    // [k][r] transposed x tile (4 KB)
    __shared__ float Wt[16][128];   // [k][j] W tile (8 KB)

    const int t  = threadIdx.x;
    const int r0 = blockIdx.x * 64;
    const int tc = t & 15;          // col group: cols tc*8 .. tc*8+7
    const int tr = t >> 4;          // row group: rows tr*4 .. tr*4+3

    float acc[4][8];
#pragma unroll
    for (int i = 0; i < 4; ++i)
#pragma unroll
        for (int j = 0; j < 8; ++j) acc[i][j] = 0.0f;

    const int lr = t >> 2;          // 0..63: row within tile for x load
    const int lq = t & 3;           // quad: k-offset lq*4 for x load
    const int wk = t >> 4;          // 0..15: k row for W load
    const int wj = (t & 15) * 8;    // col for W load

    for (int k0 = 0; k0 < kInF; k0 += 16) {
        // Stage x tile (transposed) -- float4 global load, scalar LDS stores.
        float4 xv = make_float4(0.f, 0.f, 0.f, 0.f);
        if (r0 + lr < kNodes)
            xv = *reinterpret_cast<const float4*>(x + (size_t)(r0 + lr) * kInF + k0 + lq * 4);
        xT[lq * 4 + 0][lr] = xv.x;
        xT[lq * 4 + 1][lr] = xv.y;
        xT[lq * 4 + 2][lr] = xv.z;
        xT[lq * 4 + 3][lr] = xv.w;
        // Stage W tile (no transpose needed).
        float4 w0 = *reinterpret_cast<const float4*>(W + (size_t)(k0 + wk) * kOutF + wj);
        float4 w1 = *reinterpret_cast<const float4*>(W + (size_t)(k0 + wk) * kOutF + wj + 4);
        *reinterpret_cast<float4*>(&Wt[wk][wj])     = w0;
        *reinterpret_cast<float4*>(&Wt[wk][wj + 4]) = w1;
        __syncthreads();

#pragma unroll
        for (int kk = 0; kk < 16; ++kk) {
            const float4 xr = *reinterpret_cast<const float4*>(&xT[kk][tr * 4]);
            const float4 wa = *reinterpret_cast<const float4*>(&Wt[kk][tc * 8]);
            const float4 wb = *reinterpret_cast<const float4*>(&Wt[kk][tc * 8 + 4]);
            const float xs[4] = {xr.x, xr.y, xr.z, xr.w};
            const float ws[8] = {wa.x, wa.y, wa.z, wa.w, wb.x, wb.y, wb.z, wb.w};
#pragma unroll
            for (int i = 0; i < 4; ++i)
#pragma unroll
                for (int j = 0; j < 8; ++j) acc[i][j] += xs[i] * ws[j];
        }
        __syncthreads();
    }

    // Epilogue: add bias, store.
    const float4 bv0 = *reinterpret_cast<const float4*>(b + tc * 8);
    const float4 bv1 = *reinterpret_cast<const float4*>(b + tc * 8 + 4);
    const float bb[8] = {bv0.x, bv0.y, bv0.z, bv0.w, bv1.x, bv1.y, bv1.z, bv1.w};
#pragma unroll
    for (int i = 0; i < 4; ++i) {
        const int r = r0 + tr * 4 + i;
        if (r < kNodes) {
            float4 o0 = make_float4(acc[i][0] + bb[0], acc[i][1] + bb[1],
                                    acc[i][2] + bb[2], acc[i][3] + bb[3]);
            float4 o1 = make_float4(acc[i][4] + bb[4], acc[i][5] + bb[5],
                                    acc[i][6] + bb[6], acc[i][7] + bb[7]);
            *reinterpret_cast<float4*>(support + (size_t)r * kOutF + tc * 8)     = o0;
            *reinterpret_cast<float4*>(support + (size_t)r * kOutF + tc * 8 + 4) = o1;
        }
    }
}

// ---------------------------------------------------------------------------
// Scatter: one wave per edge, lane l handles features l and l+64.
// out[row] += val * support[col]  via atomicAdd (baseline; unsorted rows).
// ---------------------------------------------------------------------------
__global__ __launch_bounds__(256) void gcn_scatter(const int* __restrict__ erow,
                                                   const int* __restrict__ ecol,
                                                   const float* __restrict__ eval,
                                                   const float* __restrict__ support,
                                                   float* __restrict__ out) {
    const int lane   = threadIdx.x & 63;
    const int wave   = blockIdx.x * (blockDim.x >> 6) + (threadIdx.x >> 6);
    const int nwaves = gridDim.x * (blockDim.x >> 6);
    for (int e = wave; e < kEdges; e += nwaves) {
        const int   r = erow[e];
        const int   c = ecol[e];
        const float v = eval[e];
        const float* s = support + (size_t)c * kOutF;
        float*       o = out + (size_t)r * kOutF;
        atomicAdd(o + lane,      v * s[lane]);
        atomicAdd(o + lane + 64, v * s[lane + 64]);
    }
}

// ---------------------------------------------------------------------------
// ReLU in place over the aggregated output.
// ---------------------------------------------------------------------------
__global__ __launch_bounds__(256) void gcn_relu(float* __restrict__ out) {
    const int total = kNodes * kOutF / 4;
    const int stride = gridDim.x * blockDim.x;
    for (int i = blockIdx.x * blockDim.x + threadIdx.x; i < total; i += stride) {
        float4 v = reinterpret_cast<float4*>(out)[i];
        v.x = fmaxf(v.x, 0.f);
        v.y = fmaxf(v.y, 0.f);
        v.z = fmaxf(v.z, 0.f);
        v.w = fmaxf(v.w, 0.f);
        reinterpret_cast<float4*>(out)[i] = v;
    }
}

extern "C" void kernel_launch(void* const* d_in, const int* in_sizes, int n_in,
                              void* d_out, int out_size, void* d_ws, size_t ws_size,
                              hipStream_t stream) {
    const float* x    = (const float*)d_in[0];
    const int*   erow = (const int*)  d_in[1];
    const int*   ecol = (const int*)  d_in[2];
    const float* eval = (const float*)d_in[3];
    const float* W    = (const float*)d_in[4];
    const float* b    = (const float*)d_in[5];
    float* out = (float*)d_out;
    float* support = (float*)d_ws;   // 100000*128*4 = 51.2 MB scratch

    // 1) support = x@W + b
    gcn_gemm<<<(kNodes + 63) / 64, 256, 0, stream>>>(x, W, b, support);
    // 2) zero output (harness poisons d_out with 0xAA)
    hipMemsetAsync(d_out, 0, (size_t)kNodes * kOutF * sizeof(float), stream);
    // 3) edge scatter with atomics
    gcn_scatter<<<2048, 256, 0, stream>>>(erow, ecol, eval, support, out);
    // 4) relu
    gcn_relu<<<2048, 256, 0, stream>>>(out);
}

// Round 2
// 612.472 us; speedup vs baseline: 1.4699x; 1.4699x over previous
//
#include <hip/hip_runtime.h>

// GCN layer: out = relu(segment_sum(edge_val * (x@W + b)[edge_col] -> edge_row))
// N=100000 nodes, E=1600000 edges, 256 -> 128 features, all fp32.
//
// Round 2: replace atomic scatter (648 us, 819 MB atomic write-through) with
// device-built CSR (histogram + scan + bucket) and a gather-aggregate kernel
// that writes each output element exactly once, relu fused.

constexpr int kNodes = 100000;
constexpr int kEdges = 1600000;
constexpr int kInF   = 256;
constexpr int kOutF  = 128;
constexpr int kScanBlocks = (kNodes + 255) / 256;   // 391

// ---------------------------------------------------------------------------
// GEMM: support[N][128] = x[N][256] @ W[256][128] + b  (fp32 vector ALU)
// ---------------------------------------------------------------------------
__global__ __launch_bounds__(256) void gcn_gemm(const float* __restrict__ x,
                                                const float* __restrict__ W,
                                                const float* __restrict__ b,
                                                float* __restrict__ support) {
    __shared__ float xT[16][64];
    __shared__ float Wt[16][128];

    const int t  = threadIdx.x;
    const int r0 = blockIdx.x * 64;
    const int tc = t & 15;
    const int tr = t >> 4;

    float acc[4][8];
#pragma unroll
    for (int i = 0; i < 4; ++i)
#pragma unroll
        for (int j = 0; j < 8; ++j) acc[i][j] = 0.0f;

    const int lr = t >> 2;
    const int lq = t & 3;
    const int wk = t >> 4;
    const int wj = (t & 15) * 8;

    for (int k0 = 0; k0 < kInF; k0 += 16) {
        float4 xv = make_float4(0.f, 0.f, 0.f, 0.f);
        if (r0 + lr < kNodes)
            xv = *reinterpret_cast<const float4*>(x + (size_t)(r0 + lr) * kInF + k0 + lq * 4);
        xT[lq * 4 + 0][lr] = xv.x;
        xT[lq * 4 + 1][lr] = xv.y;
        xT[lq * 4 + 2][lr] = xv.z;
        xT[lq * 4 + 3][lr] = xv.w;
        float4 w0 = *reinterpret_cast<const float4*>(W + (size_t)(k0 + wk) * kOutF + wj);
        float4 w1 = *reinterpret_cast<const float4*>(W + (size_t)(k0 + wk) * kOutF + wj + 4);
        *reinterpret_cast<float4*>(&Wt[wk][wj])     = w0;
        *reinterpret_cast<float4*>(&Wt[wk][wj + 4]) = w1;
        __syncthreads();

#pragma unroll
        for (int kk = 0; kk < 16; ++kk) {
            const float4 xr = *reinterpret_cast<const float4*>(&xT[kk][tr * 4]);
            const float4 wa = *reinterpret_cast<const float4*>(&Wt[kk][tc * 8]);
            const float4 wb = *reinterpret_cast<const float4*>(&Wt[kk][tc * 8 + 4]);
            const float xs[4] = {xr.x, xr.y, xr.z, xr.w};
            const float ws[8] = {wa.x, wa.y, wa.z, wa.w, wb.x, wb.y, wb.z, wb.w};
#pragma unroll
            for (int i = 0; i < 4; ++i)
#pragma unroll
                for (int j = 0; j < 8; ++j) acc[i][j] += xs[i] * ws[j];
        }
        __syncthreads();
    }

    const float4 bv0 = *reinterpret_cast<const float4*>(b + tc * 8);
    const float4 bv1 = *reinterpret_cast<const float4*>(b + tc * 8 + 4);
    const float bb[8] = {bv0.x, bv0.y, bv0.z, bv0.w, bv1.x, bv1.y, bv1.z, bv1.w};
#pragma unroll
    for (int i = 0; i < 4; ++i) {
        const int r = r0 + tr * 4 + i;
        if (r < kNodes) {
            float4 o0 = make_float4(acc[i][0] + bb[0], acc[i][1] + bb[1],
                                    acc[i][2] + bb[2], acc[i][3] + bb[3]);
            float4 o1 = make_float4(acc[i][4] + bb[4], acc[i][5] + bb[5],
                                    acc[i][6] + bb[6], acc[i][7] + bb[7]);
            *reinterpret_cast<float4*>(support + (size_t)r * kOutF + tc * 8)     = o0;
            *reinterpret_cast<float4*>(support + (size_t)r * kOutF + tc * 8 + 4) = o1;
        }
    }
}

// ---------------------------------------------------------------------------
// CSR build step 1: per-row edge counts (int atomics, cache-resident).
// ---------------------------------------------------------------------------
__global__ __launch_bounds__(256) void gcn_hist(const int* __restrict__ erow,
                                                int* __restrict__ counts) {
    const int stride = gridDim.x * blockDim.x;
    for (int e = blockIdx.x * blockDim.x + threadIdx.x; e < kEdges; e += stride)
        atomicAdd(&counts[erow[e]], 1);
}

// ---------------------------------------------------------------------------
// CSR build step 2a: block-level exclusive scan of counts -> row_start
// (exclusive within block), plus per-block totals.
// ---------------------------------------------------------------------------
__global__ __launch_bounds__(256) void gcn_scan1(const int* __restrict__ counts,
                                                 int* __restrict__ row_start,
                                                 int* __restrict__ blockSums) {
    __shared__ int s[256];
    const int i = blockIdx.x * 256 + threadIdx.x;
    const int v = (i < kNodes) ? counts[i] : 0;
    s[threadIdx.x] = v;
    __syncthreads();
#pragma unroll
    for (int off = 1; off < 256; off <<= 1) {
        const int t = (threadIdx.x >= off) ? s[threadIdx.x - off] : 0;
        __syncthreads();
        s[threadIdx.x] += t;
        __syncthreads();
    }
    if (i < kNodes) row_start[i] = s[threadIdx.x] - v;   // exclusive
    if (threadIdx.x == 255) blockSums[blockIdx.x] = s[255];
}

// ---------------------------------------------------------------------------
// CSR build step 2b: exclusive scan of the 391 block sums (one block).
// ---------------------------------------------------------------------------
__global__ __launch_bounds__(512) void gcn_scan2(const int* __restrict__ blockSums,
                                                 int* __restrict__ blockOffs) {
    __shared__ int s[512];
    const int v = (threadIdx.x < kScanBlocks) ? blockSums[threadIdx.x] : 0;
    s[threadIdx.x] = v;
    __syncthreads();
#pragma unroll
    for (int off = 1; off < 512; off <<= 1) {
        const int t = (threadIdx.x >= off) ? s[threadIdx.x - off] : 0;
        __syncthreads();
        s[threadIdx.x] += t;
        __syncthreads();
    }
    if (threadIdx.x < kScanBlocks) blockOffs[threadIdx.x] = s[threadIdx.x] - v;
}

// ---------------------------------------------------------------------------
// CSR build step 2c: add block offsets; init write cursors; cap row_start.
// ---------------------------------------------------------------------------
__global__ __launch_bounds__(256) void gcn_scan3(int* __restrict__ row_start,
                                                 const int* __restrict__ blockOffs,
                                                 int* __restrict__ cursor) {
    const int i = blockIdx.x * 256 + threadIdx.x;
    if (i < kNodes) {
        const int rs = row_start[i] + blockOffs[blockIdx.x];
        row_start[i] = rs;
        cursor[i]    = rs;
    }
    if (i == 0) row_start[kNodes] = kEdges;
}

// ---------------------------------------------------------------------------
// CSR build step 3: bucket-scatter packed (col, val) pairs by row.
// ---------------------------------------------------------------------------
__global__ __launch_bounds__(256) void gcn_bucket(const int* __restrict__ erow,
                                                  const int* __restrict__ ecol,
                                                  const float* __restrict__ eval,
                                                  int* __restrict__ cursor,
                                                  int2* __restrict__ packed) {
    const int stride = gridDim.x * blockDim.x;
    for (int e = blockIdx.x * blockDim.x + threadIdx.x; e < kEdges; e += stride) {
        const int r   = erow[e];
        const int pos = atomicAdd(&cursor[r], 1);
        packed[pos] = make_int2(ecol[e], __float_as_int(eval[e]));
    }
}

// ---------------------------------------------------------------------------
// Aggregate + ReLU: 128 threads per node (block = 2 nodes), one thread per
// output feature. Reads of support[col*128+f] are coalesced 512 B per node
// per edge; support (51.2 MB) is L3-resident. One store per output element.
// ---------------------------------------------------------------------------
__global__ __launch_bounds__(256) void gcn_aggregate(const int* __restrict__ row_start,
                                                     const int2* __restrict__ packed,
                                                     const float* __restrict__ support,
                                                     float* __restrict__ out) {
    const int n = blockIdx.x * 2 + (threadIdx.x >> 7);
    const int f = threadIdx.x & 127;
    if (n >= kNodes) return;
    const int s0 = row_start[n];
    const int s1 = row_start[n + 1];
    float acc = 0.0f;
    int i = s0;
    // unroll-by-2 to keep two gathers in flight
    for (; i + 1 < s1; i += 2) {
        const int2 p0 = packed[i];
        const int2 p1 = packed[i + 1];
        const float a0 = support[(size_t)p0.x * kOutF + f];
        const float a1 = support[(size_t)p1.x * kOutF + f];
        acc += __int_as_float(p0.y) * a0;
        acc += __int_as_float(p1.y) * a1;
    }
    if (i < s1) {
        const int2 p = packed[i];
        acc += __int_as_float(p.y) * support[(size_t)p.x * kOutF + f];
    }
    out[(size_t)n * kOutF + f] = fmaxf(acc, 0.0f);
}

extern "C" void kernel_launch(void* const* d_in, const int* in_sizes, int n_in,
                              void* d_out, int out_size, void* d_ws, size_t ws_size,
                              hipStream_t stream) {
    const float* x    = (const float*)d_in[0];
    const int*   erow = (const int*)  d_in[1];
    const int*   ecol = (const int*)  d_in[2];
    const float* eval = (const float*)d_in[3];
    const float* W    = (const float*)d_in[4];
    const float* b    = (const float*)d_in[5];
    float* out = (float*)d_out;

    // Workspace layout (bytes):
    char* ws = (char*)d_ws;
    float* support   = (float*)(ws);                       // 51,200,000 B
    int2*  packed    = (int2*) (ws + 51200000);            // 12,800,000 B
    int*   counts    = (int*)  (ws + 64000000);            //    400,000 B
    int*   row_start = (int*)  (ws + 64400000);            //    400,004 B (+pad)
    int*   cursor    = (int*)  (ws + 64800008);            //    400,000 B
    int*   blockSums = (int*)  (ws + 65200008);            //      1,564 B
    int*   blockOffs = (int*)  (ws + 65201576);            //      1,564 B
    // total ~65.2 MB

    // 1) support = x@W + b
    gcn_gemm<<<(kNodes + 63) / 64, 256, 0, stream>>>(x, W, b, support);

    // 2) CSR build
    hipMemsetAsync(counts, 0, (size_t)kNodes * sizeof(int), stream);
    gcn_hist  <<<1024, 256, 0, stream>>>(erow, counts);
    gcn_scan1 <<<kScanBlocks, 256, 0, stream>>>(counts, row_start, blockSums);
    gcn_scan2 <<<1, 512, 0, stream>>>(blockSums, blockOffs);
    gcn_scan3 <<<kScanBlocks, 256, 0, stream>>>(row_start, blockOffs, cursor);
    gcn_bucket<<<1024, 256, 0, stream>>>(erow, ecol, eval, cursor, packed);

    // 3) aggregate + relu (one write per output element, no atomics)
    gcn_aggregate<<<kNodes / 2, 256, 0, stream>>>(row_start, packed, support, out);
}

// Round 3
// 558.671 us; speedup vs baseline: 1.6115x; 1.0963x over previous
//
#include <hip/hip_runtime.h>

// GCN layer: out = relu(segment_sum(edge_val * (x@W + b)[edge_col] -> edge_row))
// N=100000 nodes, E=1600000 edges, 256 -> 128 features, all fp32.
//
// Round 3: (a) GEMM -> bf16x2 split-precision MFMA (3 MFMA terms, ~fp32
// accuracy, memory-bound ~153 MB traffic); (b) aggregate with float4 gathers
// + unroll-4 for memory-level parallelism.

constexpr int kNodes = 100000;
constexpr int kEdges = 1600000;
constexpr int kInF   = 256;
constexpr int kOutF  = 128;
constexpr int kScanBlocks = (kNodes + 255) / 256;   // 391

typedef __attribute__((ext_vector_type(8))) short short8;
typedef __attribute__((ext_vector_type(4))) short sh4;
typedef __attribute__((ext_vector_type(4))) float floatx4;

__device__ inline unsigned short f2bf_rne(float f) {
    unsigned int u = __float_as_uint(f);
    unsigned int r = u + 0x7FFFu + ((u >> 16) & 1u);
    return (unsigned short)(r >> 16);
}
__device__ inline float bf2f(unsigned short h) {
    return __uint_as_float(((unsigned int)h) << 16);
}

// ---------------------------------------------------------------------------
// GEMM: support[N][128] = x[N][256] @ W[256][128] + b
// bf16x2 split: x = xh + xl, W = Wh + Wl; x@W ~= xh Wh + xh Wl + xl Wh.
// Block: 256 thr (4 waves), tile 128x128, K-chunk 32, mfma_f32_16x16x32_bf16.
// Wave w owns rows w*32..w*32+31 (2 row-tiles), all 8 col-tiles.
// ---------------------------------------------------------------------------
__global__ __launch_bounds__(256) void gcn_gemm(const float* __restrict__ x,
                                                const float* __restrict__ W,
                                                const float* __restrict__ b,
                                                float* __restrict__ support) {
    // LDS: [row][k] layout, row stride 40 shorts (80 B) to break bank strides.
    __shared__ short Ah[128][40];
    __shared__ short Al[128][40];
    __shared__ short Bh[128][40];   // [n][k] (transposed W)
    __shared__ short Bl[128][40];

    const int t    = threadIdx.x;
    const int lane = t & 63;
    const int wv   = t >> 6;
    const int r0   = blockIdx.x * 128;
    const int rowl = lane & 15;     // row/col within a 16x16 tile
    const int quad = lane >> 4;     // 0..3
    const int kb   = quad * 8;      // k base within chunk

    floatx4 acc[2][8];
#pragma unroll
    for (int i = 0; i < 2; ++i)
#pragma unroll
        for (int j = 0; j < 8; ++j) acc[i][j] = (floatx4){0.f, 0.f, 0.f, 0.f};

    // staging indices
    const int a_row = t >> 3;        // 0..31 (per pass, +32*p)
    const int a_kq  = (t & 7) * 4;   // k offset 0..28 step 4
    const int w_n4  = (t & 31) * 4;  // col 0..124 step 4
    const int w_kp  = t >> 5;        // 0..7 (per pass, +8*p)

    for (int k0 = 0; k0 < kInF; k0 += 32) {
        // ---- stage A (x tile): 128 rows x 32 k, fp32 -> bf16 hi/lo ----
#pragma unroll
        for (int p = 0; p < 4; ++p) {
            const int row = p * 32 + a_row;
            const int rg  = r0 + row;
            float4 v = make_float4(0.f, 0.f, 0.f, 0.f);
            if (rg < kNodes)
                v = *reinterpret_cast<const float4*>(x + (size_t)rg * kInF + k0 + a_kq);
            const float vs[4] = {v.x, v.y, v.z, v.w};
            sh4 h, l;
#pragma unroll
            for (int i = 0; i < 4; ++i) {
                const unsigned short hh = f2bf_rne(vs[i]);
                h[i] = (short)hh;
                l[i] = (short)f2bf_rne(vs[i] - bf2f(hh));
            }
            *reinterpret_cast<sh4*>(&Ah[row][a_kq]) = h;
            *reinterpret_cast<sh4*>(&Al[row][a_kq]) = l;
        }
        // ---- stage B (W tile, transposed): 32 k x 128 n ----
#pragma unroll
        for (int p = 0; p < 4; ++p) {
            const int kk = p * 8 + w_kp;   // 0..31
            float4 v = *reinterpret_cast<const float4*>(W + (size_t)(k0 + kk) * kOutF + w_n4);
            const float vs[4] = {v.x, v.y, v.z, v.w};
#pragma unroll
            for (int i = 0; i < 4; ++i) {
                const unsigned short hh = f2bf_rne(vs[i]);
                Bh[w_n4 + i][kk] = (short)hh;
                Bl[w_n4 + i][kk] = (short)f2bf_rne(vs[i] - bf2f(hh));
            }
        }
        __syncthreads();

        // ---- MFMA phase ----
        short8 a_h[2], a_l[2];
#pragma unroll
        for (int rt = 0; rt < 2; ++rt) {
            const int r = wv * 32 + rt * 16 + rowl;
            a_h[rt] = *reinterpret_cast<const short8*>(&Ah[r][kb]);
            a_l[rt] = *reinterpret_cast<const short8*>(&Al[r][kb]);
        }
#pragma unroll
        for (int ct = 0; ct < 8; ++ct) {
            const int n = ct * 16 + rowl;
            const short8 b_h = *reinterpret_cast<const short8*>(&Bh[n][kb]);
            const short8 b_l = *reinterpret_cast<const short8*>(&Bl[n][kb]);
#pragma unroll
            for (int rt = 0; rt < 2; ++rt) {
                acc[rt][ct] = __builtin_amdgcn_mfma_f32_16x16x32_bf16(a_h[rt], b_h, acc[rt][ct], 0, 0, 0);
                acc[rt][ct] = __builtin_amdgcn_mfma_f32_16x16x32_bf16(a_h[rt], b_l, acc[rt][ct], 0, 0, 0);
                acc[rt][ct] = __builtin_amdgcn_mfma_f32_16x16x32_bf16(a_l[rt], b_h, acc[rt][ct], 0, 0, 0);
            }
        }
        __syncthreads();
    }

    // ---- epilogue: C/D layout col=lane&15, row=quad*4+reg ----
#pragma unroll
    for (int ct = 0; ct < 8; ++ct) {
        const int col = ct * 16 + rowl;
        const float bias = b[col];
#pragma unroll
        for (int rt = 0; rt < 2; ++rt) {
            const int rbase = r0 + wv * 32 + rt * 16 + quad * 4;
#pragma unroll
            for (int reg = 0; reg < 4; ++reg) {
                const int rg = rbase + reg;
                if (rg < kNodes)
                    support[(size_t)rg * kOutF + col] = acc[rt][ct][reg] + bias;
            }
        }
    }
}

// ---------------------------------------------------------------------------
// CSR build step 1: per-row edge counts.
// ---------------------------------------------------------------------------
__global__ __launch_bounds__(256) void gcn_hist(const int* __restrict__ erow,
                                                int* __restrict__ counts) {
    const int stride = gridDim.x * blockDim.x;
    for (int e = blockIdx.x * blockDim.x + threadIdx.x; e < kEdges; e += stride)
        atomicAdd(&counts[erow[e]], 1);
}

// ---------------------------------------------------------------------------
// CSR build step 2a: block-level exclusive scan + per-block totals.
// ---------------------------------------------------------------------------
__global__ __launch_bounds__(256) void gcn_scan1(const int* __restrict__ counts,
                                                 int* __restrict__ row_start,
                                                 int* __restrict__ blockSums) {
    __shared__ int s[256];
    const int i = blockIdx.x * 256 + threadIdx.x;
    const int v = (i < kNodes) ? counts[i] : 0;
    s[threadIdx.x] = v;
    __syncthreads();
#pragma unroll
    for (int off = 1; off < 256; off <<= 1) {
        const int t = (threadIdx.x >= off) ? s[threadIdx.x - off] : 0;
        __syncthreads();
        s[threadIdx.x] += t;
        __syncthreads();
    }
    if (i < kNodes) row_start[i] = s[threadIdx.x] - v;
    if (threadIdx.x == 255) blockSums[blockIdx.x] = s[255];
}

__global__ __launch_bounds__(512) void gcn_scan2(const int* __restrict__ blockSums,
                                                 int* __restrict__ blockOffs) {
    __shared__ int s[512];
    const int v = (threadIdx.x < kScanBlocks) ? blockSums[threadIdx.x] : 0;
    s[threadIdx.x] = v;
    __syncthreads();
#pragma unroll
    for (int off = 1; off < 512; off <<= 1) {
        const int t = (threadIdx.x >= off) ? s[threadIdx.x - off] : 0;
        __syncthreads();
        s[threadIdx.x] += t;
        __syncthreads();
    }
    if (threadIdx.x < kScanBlocks) blockOffs[threadIdx.x] = s[threadIdx.x] - v;
}

__global__ __launch_bounds__(256) void gcn_scan3(int* __restrict__ row_start,
                                                 const int* __restrict__ blockOffs,
                                                 int* __restrict__ cursor) {
    const int i = blockIdx.x * 256 + threadIdx.x;
    if (i < kNodes) {
        const int rs = row_start[i] + blockOffs[blockIdx.x];
        row_start[i] = rs;
        cursor[i]    = rs;
    }
    if (i == 0) row_start[kNodes] = kEdges;
}

// ---------------------------------------------------------------------------
// CSR build step 3: bucket-scatter packed (col, val) pairs by row.
// ---------------------------------------------------------------------------
__global__ __launch_bounds__(256) void gcn_bucket(const int* __restrict__ erow,
                                                  const int* __restrict__ ecol,
                                                  const float* __restrict__ eval,
                                                  int* __restrict__ cursor,
                                                  int2* __restrict__ packed) {
    const int stride = gridDim.x * blockDim.x;
    for (int e = blockIdx.x * blockDim.x + threadIdx.x; e < kEdges; e += stride) {
        const int r   = erow[e];
        const int pos = atomicAdd(&cursor[r], 1);
        packed[pos] = make_int2(ecol[e], __float_as_int(eval[e]));
    }
}

// ---------------------------------------------------------------------------
// Aggregate + ReLU: 32 threads per node (block = 8 nodes), float4 per thread,
// 4 edges in flight. One float4 store per thread.
// ---------------------------------------------------------------------------
__global__ __launch_bounds__(256) void gcn_aggregate(const int* __restrict__ row_start,
                                                     const int2* __restrict__ packed,
                                                     const float* __restrict__ support,
                                                     float* __restrict__ out) {
    const int n  = blockIdx.x * 8 + (threadIdx.x >> 5);
    const int f4 = (threadIdx.x & 31) * 4;
    if (n >= kNodes) return;
    const int s0 = row_start[n];
    const int s1 = row_start[n + 1];
    float4 acc = make_float4(0.f, 0.f, 0.f, 0.f);
    int i = s0;
    for (; i + 3 < s1; i += 4) {
        const int2 p0 = packed[i];
        const int2 p1 = packed[i + 1];
        const int2 p2 = packed[i + 2];
        const int2 p3 = packed[i + 3];
        const float4 a0 = *reinterpret_cast<const float4*>(support + (size_t)p0.x * kOutF + f4);
        const float4 a1 = *reinterpret_cast<const float4*>(support + (size_t)p1.x * kOutF + f4);
        const float4 a2 = *reinterpret_cast<const float4*>(support + (size_t)p2.x * kOutF + f4);
        const float4 a3 = *reinterpret_cast<const float4*>(support + (size_t)p3.x * kOutF + f4);
        const float v0 = __int_as_float(p0.y), v1 = __int_as_float(p1.y);
        const float v2 = __int_as_float(p2.y), v3 = __int_as_float(p3.y);
        acc.x += v0 * a0.x + v1 * a1.x + v2 * a2.x + v3 * a3.x;
        acc.y += v0 * a0.y + v1 * a1.y + v2 * a2.y + v3 * a3.y;
        acc.z += v0 * a0.z + v1 * a1.z + v2 * a2.z + v3 * a3.z;
        acc.w += v0 * a0.w + v1 * a1.w + v2 * a2.w + v3 * a3.w;
    }
    for (; i < s1; ++i) {
        const int2 p = packed[i];
        const float v = __int_as_float(p.y);
        const float4 a = *reinterpret_cast<const float4*>(support + (size_t)p.x * kOutF + f4);
        acc.x += v * a.x; acc.y += v * a.y; acc.z += v * a.z; acc.w += v * a.w;
    }
    float4 o = make_float4(fmaxf(acc.x, 0.f), fmaxf(acc.y, 0.f),
                           fmaxf(acc.z, 0.f), fmaxf(acc.w, 0.f));
    *reinterpret_cast<float4*>(out + (size_t)n * kOutF + f4) = o;
}

extern "C" void kernel_launch(void* const* d_in, const int* in_sizes, int n_in,
                              void* d_out, int out_size, void* d_ws, size_t ws_size,
                              hipStream_t stream) {
    const float* x    = (const float*)d_in[0];
    const int*   erow = (const int*)  d_in[1];
    const int*   ecol = (const int*)  d_in[2];
    const float* eval = (const float*)d_in[3];
    const float* W    = (const float*)d_in[4];
    const float* b    = (const float*)d_in[5];
    float* out = (float*)d_out;

    char* ws = (char*)d_ws;
    float* support   = (float*)(ws);                       // 51,200,000 B
    int2*  packed    = (int2*) (ws + 51200000);            // 12,800,000 B
    int*   counts    = (int*)  (ws + 64000000);            //    400,000 B
    int*   row_start = (int*)  (ws + 64400000);            //    400,004 B
    int*   cursor    = (int*)  (ws + 64800008);            //    400,000 B
    int*   blockSums = (int*)  (ws + 65200008);            //      1,564 B
    int*   blockOffs = (int*)  (ws + 65201576);            //      1,564 B

    // 1) support = x@W + b (bf16x2 split MFMA)
    gcn_gemm<<<(kNodes + 127) / 128, 256, 0, stream>>>(x, W, b, support);

    // 2) CSR build
    hipMemsetAsync(counts, 0, (size_t)kNodes * sizeof(int), stream);
    gcn_hist  <<<1024, 256, 0, stream>>>(erow, counts);
    gcn_scan1 <<<kScanBlocks, 256, 0, stream>>>(counts, row_start, blockSums);
    gcn_scan2 <<<1, 512, 0, stream>>>(blockSums, blockOffs);
    gcn_scan3 <<<kScanBlocks, 256, 0, stream>>>(row_start, blockOffs, cursor);
    gcn_bucket<<<1024, 256, 0, stream>>>(erow, ecol, eval, cursor, packed);

    // 3) aggregate + relu
    gcn_aggregate<<<(kNodes + 7) / 8, 256, 0, stream>>>(row_start, packed, support, out);
}

// Round 4
// 451.990 us; speedup vs baseline: 1.9918x; 1.2360x over previous
//
#include <hip/hip_runtime.h>

// GCN layer: out = relu(segment_sum(edge_val * (x@W + b)[edge_col] -> edge_row))
// N=100000 nodes, E=1600000 edges, 256 -> 128 features, fp32 in/out.
//
// Round 4: (a) bucket: batch 8 independent cursor-atomics per thread (kill the
// dependent-latency chain measured at 130 us, VALUBusy 0.3%); (b) support in
// bf16 (halves gather+write traffic; error budget ~0.1 << 0.36 threshold);
// (c) plain-bf16 MFMA GEMM (drop bf16x2 lo-terms); (d) aggregate with 16
// lanes/node, bf16x8 gathers, unroll-4.

constexpr int kNodes = 100000;
constexpr int kEdges = 1600000;
constexpr int kInF   = 256;
constexpr int kOutF  = 128;
constexpr int kScanBlocks = (kNodes + 255) / 256;   // 391
constexpr int kBucketBlocks = 800;                  // 800*256*8 = 1,638,400 >= E

typedef __attribute__((ext_vector_type(8))) short short8;
typedef __attribute__((ext_vector_type(4))) short sh4;
typedef __attribute__((ext_vector_type(8))) unsigned short ush8;
typedef __attribute__((ext_vector_type(4))) float floatx4;

__device__ inline unsigned short f2bf_rne(float f) {
    unsigned int u = __float_as_uint(f);
    unsigned int r = u + 0x7FFFu + ((u >> 16) & 1u);
    return (unsigned short)(r >> 16);
}
__device__ inline float bf2f(unsigned short h) {
    return __uint_as_float(((unsigned int)h) << 16);
}

// ---------------------------------------------------------------------------
// GEMM: support_bf[N][128] = bf16(x[N][256] @ W[256][128] + b)
// Plain bf16 MFMA (16x16x32), block 256 thr / tile 128x128 / K-chunk 32.
// ---------------------------------------------------------------------------
__global__ __launch_bounds__(256) void gcn_gemm(const float* __restrict__ x,
                                                const float* __restrict__ W,
                                                const float* __restrict__ b,
                                                unsigned short* __restrict__ support) {
    __shared__ short Ah[128][40];   // [row][k], +8 pad
    __shared__ short Bh[128][40];   // [n][k] (transposed W)

    const int t    = threadIdx.x;
    const int lane = t & 63;
    const int wv   = t >> 6;
    const int r0   = blockIdx.x * 128;
    const int rowl = lane & 15;
    const int quad = lane >> 4;
    const int kb   = quad * 8;

    floatx4 acc[2][8];
#pragma unroll
    for (int i = 0; i < 2; ++i)
#pragma unroll
        for (int j = 0; j < 8; ++j) acc[i][j] = (floatx4){0.f, 0.f, 0.f, 0.f};

    const int a_row = t >> 3;        // 0..31 (+32*p)
    const int a_kq  = (t & 7) * 4;   // 0..28 step 4
    const int w_n4  = (t & 31) * 4;  // 0..124 step 4
    const int w_kp  = t >> 5;        // 0..7 (+8*p)

    for (int k0 = 0; k0 < kInF; k0 += 32) {
#pragma unroll
        for (int p = 0; p < 4; ++p) {
            const int row = p * 32 + a_row;
            const int rg  = r0 + row;
            float4 v = make_float4(0.f, 0.f, 0.f, 0.f);
            if (rg < kNodes)
                v = *reinterpret_cast<const float4*>(x + (size_t)rg * kInF + k0 + a_kq);
            sh4 h;
            h[0] = (short)f2bf_rne(v.x);
            h[1] = (short)f2bf_rne(v.y);
            h[2] = (short)f2bf_rne(v.z);
            h[3] = (short)f2bf_rne(v.w);
            *reinterpret_cast<sh4*>(&Ah[row][a_kq]) = h;
        }
#pragma unroll
        for (int p = 0; p < 4; ++p) {
            const int kk = p * 8 + w_kp;
            float4 v = *reinterpret_cast<const float4*>(W + (size_t)(k0 + kk) * kOutF + w_n4);
            Bh[w_n4 + 0][kk] = (short)f2bf_rne(v.x);
            Bh[w_n4 + 1][kk] = (short)f2bf_rne(v.y);
            Bh[w_n4 + 2][kk] = (short)f2bf_rne(v.z);
            Bh[w_n4 + 3][kk] = (short)f2bf_rne(v.w);
        }
        __syncthreads();

        short8 a_f[2];
#pragma unroll
        for (int rt = 0; rt < 2; ++rt)
            a_f[rt] = *reinterpret_cast<const short8*>(&Ah[wv * 32 + rt * 16 + rowl][kb]);
#pragma unroll
        for (int ct = 0; ct < 8; ++ct) {
            const short8 b_f = *reinterpret_cast<const short8*>(&Bh[ct * 16 + rowl][kb]);
#pragma unroll
            for (int rt = 0; rt < 2; ++rt)
                acc[rt][ct] = __builtin_amdgcn_mfma_f32_16x16x32_bf16(a_f[rt], b_f, acc[rt][ct], 0, 0, 0);
        }
        __syncthreads();
    }

    // C/D layout: col = lane&15, row = quad*4 + reg (verified r3).
#pragma unroll
    for (int ct = 0; ct < 8; ++ct) {
        const int col = ct * 16 + rowl;
        const float bias = b[col];
#pragma unroll
        for (int rt = 0; rt < 2; ++rt) {
            const int rbase = r0 + wv * 32 + rt * 16 + quad * 4;
#pragma unroll
            for (int reg = 0; reg < 4; ++reg) {
                const int rg = rbase + reg;
                if (rg < kNodes)
                    support[(size_t)rg * kOutF + col] = f2bf_rne(acc[rt][ct][reg] + bias);
            }
        }
    }
}

// ---------------------------------------------------------------------------
// CSR step 1: per-row edge counts (fire-and-forget atomics).
// ---------------------------------------------------------------------------
__global__ __launch_bounds__(256) void gcn_hist(const int* __restrict__ erow,
                                                int* __restrict__ counts) {
    const int stride = gridDim.x * blockDim.x;
    for (int e = blockIdx.x * blockDim.x + threadIdx.x; e < kEdges; e += stride)
        atomicAdd(&counts[erow[e]], 1);
}

// ---------------------------------------------------------------------------
// CSR step 2: two-level exclusive scan.
// ---------------------------------------------------------------------------
__global__ __launch_bounds__(256) void gcn_scan1(const int* __restrict__ counts,
                                                 int* __restrict__ row_start,
                                                 int* __restrict__ blockSums) {
    __shared__ int s[256];
    const int i = blockIdx.x * 256 + threadIdx.x;
    const int v = (i < kNodes) ? counts[i] : 0;
    s[threadIdx.x] = v;
    __syncthreads();
#pragma unroll
    for (int off = 1; off < 256; off <<= 1) {
        const int t = (threadIdx.x >= off) ? s[threadIdx.x - off] : 0;
        __syncthreads();
        s[threadIdx.x] += t;
        __syncthreads();
    }
    if (i < kNodes) row_start[i] = s[threadIdx.x] - v;
    if (threadIdx.x == 255) blockSums[blockIdx.x] = s[255];
}

__global__ __launch_bounds__(512) void gcn_scan2(const int* __restrict__ blockSums,
                                                 int* __restrict__ blockOffs) {
    __shared__ int s[512];
    const int v = (threadIdx.x < kScanBlocks) ? blockSums[threadIdx.x] : 0;
    s[threadIdx.x] = v;
    __syncthreads();
#pragma unroll
    for (int off = 1; off < 512; off <<= 1) {
        const int t = (threadIdx.x >= off) ? s[threadIdx.x - off] : 0;
        __syncthreads();
        s[threadIdx.x] += t;
        __syncthreads();
    }
    if (threadIdx.x < kScanBlocks) blockOffs[threadIdx.x] = s[threadIdx.x] - v;
}

__global__ __launch_bounds__(256) void gcn_scan3(int* __restrict__ row_start,
                                                 const int* __restrict__ blockOffs,
                                                 int* __restrict__ cursor) {
    const int i = blockIdx.x * 256 + threadIdx.x;
    if (i < kNodes) {
        const int rs = row_start[i] + blockOffs[blockIdx.x];
        row_start[i] = rs;
        cursor[i]    = rs;
    }
    if (i == 0) row_start[kNodes] = kEdges;
}

// ---------------------------------------------------------------------------
// CSR step 3: bucket-scatter with 8 BATCHED independent atomics per thread.
// (r3 version chained ~6 dependent 500-cyc atomic round trips -> 130 us.)
// ---------------------------------------------------------------------------
__global__ __launch_bounds__(256) void gcn_bucket(const int* __restrict__ erow,
                                                  const int* __restrict__ ecol,
                                                  const float* __restrict__ eval,
                                                  int* __restrict__ cursor,
                                                  int2* __restrict__ packed) {
    const int T   = kBucketBlocks * 256;
    const int tid = blockIdx.x * 256 + threadIdx.x;
    int r[8], c[8], pos[8];
    float v[8];
#pragma unroll
    for (int i = 0; i < 8; ++i) {
        const int e = tid + i * T;
        const bool ok = (e < kEdges);
        r[i] = ok ? erow[e] : 0;
        c[i] = ok ? ecol[e] : 0;
        v[i] = ok ? eval[e] : 0.f;
    }
#pragma unroll
    for (int i = 0; i < 8; ++i) {
        const int e = tid + i * T;
        pos[i] = (e < kEdges) ? atomicAdd(&cursor[r[i]], 1) : 0;
    }
#pragma unroll
    for (int i = 0; i < 8; ++i) {
        const int e = tid + i * T;
        if (e < kEdges) packed[pos[i]] = make_int2(c[i], __float_as_int(v[i]));
    }
}

// ---------------------------------------------------------------------------
// Aggregate + ReLU: 16 lanes/node (block = 16 nodes), bf16x8 (16 B) gathers,
// fp32 accumulate, unroll-4 edges for MLP. One fp32 row write per node.
// ---------------------------------------------------------------------------
__global__ __launch_bounds__(256) void gcn_aggregate(const int* __restrict__ row_start,
                                                     const int2* __restrict__ packed,
                                                     const unsigned short* __restrict__ support,
                                                     float* __restrict__ out) {
    const int n  = blockIdx.x * 16 + (threadIdx.x >> 4);
    const int f8 = (threadIdx.x & 15) * 8;
    if (n >= kNodes) return;
    const int s0 = row_start[n];
    const int s1 = row_start[n + 1];
    float acc[8];
#pragma unroll
    for (int j = 0; j < 8; ++j) acc[j] = 0.f;

    int i = s0;
    for (; i + 3 < s1; i += 4) {
        const int2 p0 = packed[i];
        const int2 p1 = packed[i + 1];
        const int2 p2 = packed[i + 2];
        const int2 p3 = packed[i + 3];
        const ush8 a0 = *reinterpret_cast<const ush8*>(support + (size_t)p0.x * kOutF + f8);
        const ush8 a1 = *reinterpret_cast<const ush8*>(support + (size_t)p1.x * kOutF + f8);
        const ush8 a2 = *reinterpret_cast<const ush8*>(support + (size_t)p2.x * kOutF + f8);
        const ush8 a3 = *reinterpret_cast<const ush8*>(support + (size_t)p3.x * kOutF + f8);
        const float v0 = __int_as_float(p0.y), v1 = __int_as_float(p1.y);
        const float v2 = __int_as_float(p2.y), v3 = __int_as_float(p3.y);
#pragma unroll
        for (int j = 0; j < 8; ++j) {
            acc[j] += v0 * bf2f(a0[j]);
            acc[j] += v1 * bf2f(a1[j]);
            acc[j] += v2 * bf2f(a2[j]);
            acc[j] += v3 * bf2f(a3[j]);
        }
    }
    for (; i < s1; ++i) {
        const int2 p = packed[i];
        const float v = __int_as_float(p.y);
        const ush8 a = *reinterpret_cast<const ush8*>(support + (size_t)p.x * kOutF + f8);
#pragma unroll
        for (int j = 0; j < 8; ++j) acc[j] += v * bf2f(a[j]);
    }

    float4 o0 = make_float4(fmaxf(acc[0], 0.f), fmaxf(acc[1], 0.f),
                            fmaxf(acc[2], 0.f), fmaxf(acc[3], 0.f));
    float4 o1 = make_float4(fmaxf(acc[4], 0.f), fmaxf(acc[5], 0.f),
                            fmaxf(acc[6], 0.f), fmaxf(acc[7], 0.f));
    *reinterpret_cast<float4*>(out + (size_t)n * kOutF + f8)     = o0;
    *reinterpret_cast<float4*>(out + (size_t)n * kOutF + f8 + 4) = o1;
}

extern "C" void kernel_launch(void* const* d_in, const int* in_sizes, int n_in,
                              void* d_out, int out_size, void* d_ws, size_t ws_size,
                              hipStream_t stream) {
    const float* x    = (const float*)d_in[0];
    const int*   erow = (const int*)  d_in[1];
    const int*   ecol = (const int*)  d_in[2];
    const float* eval = (const float*)d_in[3];
    const float* W    = (const float*)d_in[4];
    const float* b    = (const float*)d_in[5];
    float* out = (float*)d_out;

    char* ws = (char*)d_ws;
    unsigned short* support = (unsigned short*)(ws);       // 25,600,000 B
    int2* packed    = (int2*)(ws + 25600000);              // 12,800,000 B
    int*  counts    = (int*) (ws + 38400000);              //    400,000 B
    int*  row_start = (int*) (ws + 38800000);              //    400,004 B
    int*  cursor    = (int*) (ws + 39200008);              //    400,000 B
    int*  blockSums = (int*) (ws + 39600008);              //      1,564 B
    int*  blockOffs = (int*) (ws + 39601576);              //      1,564 B

    // 1) support = bf16(x@W + b)
    gcn_gemm<<<(kNodes + 127) / 128, 256, 0, stream>>>(x, W, b, support);

    // 2) CSR build
    hipMemsetAsync(counts, 0, (size_t)kNodes * sizeof(int), stream);
    gcn_hist  <<<1024, 256, 0, stream>>>(erow, counts);
    gcn_scan1 <<<kScanBlocks, 256, 0, stream>>>(counts, row_start, blockSums);
    gcn_scan2 <<<1, 512, 0, stream>>>(blockSums, blockOffs);
    gcn_scan3 <<<kScanBlocks, 256, 0, stream>>>(row_start, blockOffs, cursor);
    gcn_bucket<<<kBucketBlocks, 256, 0, stream>>>(erow, ecol, eval, cursor, packed);

    // 3) aggregate + relu
    gcn_aggregate<<<(kNodes + 15) / 16, 256, 0, stream>>>(row_start, packed, support, out);
}

// Round 6
// 437.024 us; speedup vs baseline: 2.0600x; 1.0342x over previous
//
#include <hip/hip_runtime.h>

// GCN layer: out = relu(segment_sum(edge_val * (x@W + b)[edge_col] -> edge_row))
// N=100000 nodes, E=1600000 edges, 256 -> 128 features, fp32 in/out.
//
// Round 6: fix r5's coverage bug. r5 distributed row-tiles by global wave_id
// while each wave only wrote its wv-determined 32-col slice -> 3/4 of each
// tile's columns never written. Fix: tiles are assigned to BLOCKS; the 4
// waves of a block each cover their own 32-col slice of the same 16-row
// tile. x re-reads (4x logical) are L1/L2-local since the 4 waves run in
// near-lockstep on one CU. Still LDS-free, barrier-free.

constexpr int kNodes = 100000;
constexpr int kEdges = 1600000;
constexpr int kInF   = 256;
constexpr int kOutF  = 128;
constexpr int kScanBlocks = (kNodes + 255) / 256;   // 391
constexpr int kBucketBlocks = 800;                  // 800*256*8 >= E
constexpr int kGemmBlocks = 1250;                   // 6250 tiles / 5 per block

typedef __attribute__((ext_vector_type(8))) short short8;
typedef __attribute__((ext_vector_type(8))) unsigned short ush8;
typedef __attribute__((ext_vector_type(4))) float floatx4;

__device__ inline unsigned short f2bf_rne(float f) {
    unsigned int u = __float_as_uint(f);
    unsigned int r = u + 0x7FFFu + ((u >> 16) & 1u);
    return (unsigned short)(r >> 16);
}
__device__ inline float bf2f(unsigned short h) {
    return __uint_as_float(((unsigned int)h) << 16);
}

// ---------------------------------------------------------------------------
// GEMM: support_bf[N][128] = bf16(x[N][256] @ W[256][128] + b)
// Block = 4 waves; wave wv owns cols wv*32..wv*32+31 (2 col-tiles), B-frags
// held in 64 VGPRs (loaded once, L2-resident W). Block grid-strides over
// 6250 16-row tiles; all 4 waves process the SAME tile (different cols).
// MFMA 16x16x32 bf16. A: lane(row=lane&15, k=quad*8+j). B: lane(n=lane&15,
// k=quad*8+j) = W[k][n]. C/D: col=lane&15, row=quad*4+reg. (verified r3/r4)
// ---------------------------------------------------------------------------
__global__ __launch_bounds__(256) void gcn_gemm(const float* __restrict__ x,
                                                const float* __restrict__ W,
                                                const float* __restrict__ b,
                                                unsigned short* __restrict__ support) {
    const int lane = threadIdx.x & 63;
    const int wv   = threadIdx.x >> 6;
    const int rowl = lane & 15;
    const int quad = lane >> 4;
    const int colbase = wv * 32;

    // ---- one-time: B fragments for this wave's 32 cols (64 VGPRs) ----
    short8 bfrag[2][8];
#pragma unroll
    for (int ct = 0; ct < 2; ++ct) {
        const int col = colbase + ct * 16 + rowl;
#pragma unroll
        for (int kc = 0; kc < 8; ++kc) {
            const int kb = kc * 32 + quad * 8;
            short8 f;
#pragma unroll
            for (int j = 0; j < 8; ++j)
                f[j] = (short)f2bf_rne(W[(size_t)(kb + j) * kOutF + col]);
            bfrag[ct][kc] = f;
        }
    }
    const float bias0 = b[colbase + rowl];
    const float bias1 = b[colbase + 16 + rowl];

    // ---- block-strided 16-row tiles; all 4 waves share each tile ----
    for (int tile = blockIdx.x; tile < kNodes / 16; tile += gridDim.x) {
        const int r0 = tile * 16;
        floatx4 acc0 = {0.f, 0.f, 0.f, 0.f};
        floatx4 acc1 = {0.f, 0.f, 0.f, 0.f};
        const float* xrow = x + (size_t)(r0 + rowl) * kInF + quad * 8;
#pragma unroll
        for (int kc = 0; kc < 8; ++kc) {
            const float4 v0 = *reinterpret_cast<const float4*>(xrow + kc * 32);
            const float4 v1 = *reinterpret_cast<const float4*>(xrow + kc * 32 + 4);
            short8 a;
            a[0] = (short)f2bf_rne(v0.x);
            a[1] = (short)f2bf_rne(v0.y);
            a[2] = (short)f2bf_rne(v0.z);
            a[3] = (short)f2bf_rne(v0.w);
            a[4] = (short)f2bf_rne(v1.x);
            a[5] = (short)f2bf_rne(v1.y);
            a[6] = (short)f2bf_rne(v1.z);
            a[7] = (short)f2bf_rne(v1.w);
            acc0 = __builtin_amdgcn_mfma_f32_16x16x32_bf16(a, bfrag[0][kc], acc0, 0, 0, 0);
            acc1 = __builtin_amdgcn_mfma_f32_16x16x32_bf16(a, bfrag[1][kc], acc1, 0, 0, 0);
        }
        // epilogue: rows r0+quad*4+reg, cols colbase+{rowl, 16+rowl}
#pragma unroll
        for (int reg = 0; reg < 4; ++reg) {
            const size_t rbase = (size_t)(r0 + quad * 4 + reg) * kOutF + colbase;
            support[rbase + rowl]      = f2bf_rne(acc0[reg] + bias0);
            support[rbase + 16 + rowl] = f2bf_rne(acc1[reg] + bias1);
        }
    }
}

// ---------------------------------------------------------------------------
// CSR step 1: per-row edge counts (fire-and-forget atomics).
// ---------------------------------------------------------------------------
__global__ __launch_bounds__(256) void gcn_hist(const int* __restrict__ erow,
                                                int* __restrict__ counts) {
    const int stride = gridDim.x * blockDim.x;
    for (int e = blockIdx.x * blockDim.x + threadIdx.x; e < kEdges; e += stride)
        atomicAdd(&counts[erow[e]], 1);
}

// ---------------------------------------------------------------------------
// CSR step 2: two-level exclusive scan.
// ---------------------------------------------------------------------------
__global__ __launch_bounds__(256) void gcn_scan1(const int* __restrict__ counts,
                                                 int* __restrict__ row_start,
                                                 int* __restrict__ blockSums) {
    __shared__ int s[256];
    const int i = blockIdx.x * 256 + threadIdx.x;
    const int v = (i < kNodes) ? counts[i] : 0;
    s[threadIdx.x] = v;
    __syncthreads();
#pragma unroll
    for (int off = 1; off < 256; off <<= 1) {
        const int t = (threadIdx.x >= off) ? s[threadIdx.x - off] : 0;
        __syncthreads();
        s[threadIdx.x] += t;
        __syncthreads();
    }
    if (i < kNodes) row_start[i] = s[threadIdx.x] - v;
    if (threadIdx.x == 255) blockSums[blockIdx.x] = s[255];
}

__global__ __launch_bounds__(512) void gcn_scan2(const int* __restrict__ blockSums,
                                                 int* __restrict__ blockOffs) {
    __shared__ int s[512];
    const int v = (threadIdx.x < kScanBlocks) ? blockSums[threadIdx.x] : 0;
    s[threadIdx.x] = v;
    __syncthreads();
#pragma unroll
    for (int off = 1; off < 512; off <<= 1) {
        const int t = (threadIdx.x >= off) ? s[threadIdx.x - off] : 0;
        __syncthreads();
        s[threadIdx.x] += t;
        __syncthreads();
    }
    if (threadIdx.x < kScanBlocks) blockOffs[threadIdx.x] = s[threadIdx.x] - v;
}

__global__ __launch_bounds__(256) void gcn_scan3(int* __restrict__ row_start,
                                                 const int* __restrict__ blockOffs,
                                                 int* __restrict__ cursor) {
    const int i = blockIdx.x * 256 + threadIdx.x;
    if (i < kNodes) {
        const int rs = row_start[i] + blockOffs[blockIdx.x];
        row_start[i] = rs;
        cursor[i]    = rs;
    }
    if (i == 0) row_start[kNodes] = kEdges;
}

// ---------------------------------------------------------------------------
// CSR step 3: bucket-scatter, 8 batched independent atomics per thread.
// ---------------------------------------------------------------------------
__global__ __launch_bounds__(256) void gcn_bucket(const int* __restrict__ erow,
                                                  const int* __restrict__ ecol,
                                                  const float* __restrict__ eval,
                                                  int* __restrict__ cursor,
                                                  int2* __restrict__ packed) {
    const int T   = kBucketBlocks * 256;
    const int tid = blockIdx.x * 256 + threadIdx.x;
    int r[8], c[8], pos[8];
    float v[8];
#pragma unroll
    for (int i = 0; i < 8; ++i) {
        const int e = tid + i * T;
        const bool ok = (e < kEdges);
        r[i] = ok ? erow[e] : 0;
        c[i] = ok ? ecol[e] : 0;
        v[i] = ok ? eval[e] : 0.f;
    }
#pragma unroll
    for (int i = 0; i < 8; ++i) {
        const int e = tid + i * T;
        pos[i] = (e < kEdges) ? atomicAdd(&cursor[r[i]], 1) : 0;
    }
#pragma unroll
    for (int i = 0; i < 8; ++i) {
        const int e = tid + i * T;
        if (e < kEdges) packed[pos[i]] = make_int2(c[i], __float_as_int(v[i]));
    }
}

// ---------------------------------------------------------------------------
// Aggregate + ReLU: 16 lanes/node (block = 16 nodes), bf16x8 (16 B) gathers,
// fp32 accumulate, unroll-4 edges for MLP. One fp32 row write per node.
// ---------------------------------------------------------------------------
__global__ __launch_bounds__(256) void gcn_aggregate(const int* __restrict__ row_start,
                                                     const int2* __restrict__ packed,
                                                     const unsigned short* __restrict__ support,
                                                     float* __restrict__ out) {
    const int n  = blockIdx.x * 16 + (threadIdx.x >> 4);
    const int f8 = (threadIdx.x & 15) * 8;
    if (n >= kNodes) return;
    const int s0 = row_start[n];
    const int s1 = row_start[n + 1];
    float acc[8];
#pragma unroll
    for (int j = 0; j < 8; ++j) acc[j] = 0.f;

    int i = s0;
    for (; i + 3 < s1; i += 4) {
        const int2 p0 = packed[i];
        const int2 p1 = packed[i + 1];
        const int2 p2 = packed[i + 2];
        const int2 p3 = packed[i + 3];
        const ush8 a0 = *reinterpret_cast<const ush8*>(support + (size_t)p0.x * kOutF + f8);
        const ush8 a1 = *reinterpret_cast<const ush8*>(support + (size_t)p1.x * kOutF + f8);
        const ush8 a2 = *reinterpret_cast<const ush8*>(support + (size_t)p2.x * kOutF + f8);
        const ush8 a3 = *reinterpret_cast<const ush8*>(support + (size_t)p3.x * kOutF + f8);
        const float v0 = __int_as_float(p0.y), v1 = __int_as_float(p1.y);
        const float v2 = __int_as_float(p2.y), v3 = __int_as_float(p3.y);
#pragma unroll
        for (int j = 0; j < 8; ++j) {
            acc[j] += v0 * bf2f(a0[j]);
            acc[j] += v1 * bf2f(a1[j]);
            acc[j] += v2 * bf2f(a2[j]);
            acc[j] += v3 * bf2f(a3[j]);
        }
    }
    for (; i < s1; ++i) {
        const int2 p = packed[i];
        const float v = __int_as_float(p.y);
        const ush8 a = *reinterpret_cast<const ush8*>(support + (size_t)p.x * kOutF + f8);
#pragma unroll
        for (int j = 0; j < 8; ++j) acc[j] += v * bf2f(a[j]);
    }

    float4 o0 = make_float4(fmaxf(acc[0], 0.f), fmaxf(acc[1], 0.f),
                            fmaxf(acc[2], 0.f), fmaxf(acc[3], 0.f));
    float4 o1 = make_float4(fmaxf(acc[4], 0.f), fmaxf(acc[5], 0.f),
                            fmaxf(acc[6], 0.f), fmaxf(acc[7], 0.f));
    *reinterpret_cast<float4*>(out + (size_t)n * kOutF + f8)     = o0;
    *reinterpret_cast<float4*>(out + (size_t)n * kOutF + f8 + 4) = o1;
}

extern "C" void kernel_launch(void* const* d_in, const int* in_sizes, int n_in,
                              void* d_out, int out_size, void* d_ws, size_t ws_size,
                              hipStream_t stream) {
    const float* x    = (const float*)d_in[0];
    const int*   erow = (const int*)  d_in[1];
    const int*   ecol = (const int*)  d_in[2];
    const float* eval = (const float*)d_in[3];
    const float* W    = (const float*)d_in[4];
    const float* b    = (const float*)d_in[5];
    float* out = (float*)d_out;

    char* ws = (char*)d_ws;
    unsigned short* support = (unsigned short*)(ws);       // 25,600,000 B
    int2* packed    = (int2*)(ws + 25600000);              // 12,800,000 B
    int*  counts    = (int*) (ws + 38400000);              //    400,000 B
    int*  row_start = (int*) (ws + 38800000);              //    400,004 B
    int*  cursor    = (int*) (ws + 39200008);              //    400,000 B
    int*  blockSums = (int*) (ws + 39600008);              //      1,564 B
    int*  blockOffs = (int*) (ws + 39601576);              //      1,564 B

    // 1) support = bf16(x@W + b)  -- LDS-free, barrier-free, tile-per-block
    gcn_gemm<<<kGemmBlocks, 256, 0, stream>>>(x, W, b, support);

    // 2) CSR build
    hipMemsetAsync(counts, 0, (size_t)kNodes * sizeof(int), stream);
    gcn_hist  <<<1024, 256, 0, stream>>>(erow, counts);
    gcn_scan1 <<<kScanBlocks, 256, 0, stream>>>(counts, row_start, blockSums);
    gcn_scan2 <<<1, 512, 0, stream>>>(blockSums, blockOffs);
    gcn_scan3 <<<kScanBlocks, 256, 0, stream>>>(row_start, blockOffs, cursor);
    gcn_bucket<<<kBucketBlocks, 256, 0, stream>>>(erow, ecol, eval, cursor, packed);

    // 3) aggregate + relu
    gcn_aggregate<<<(kNodes + 15) / 16, 256, 0, stream>>>(row_start, packed, support, out);
}